// Round 1
// 848.697 us; speedup vs baseline: 1.4517x; 1.4517x over previous
//
#include <hip/hip_runtime.h>
#include <cstdint>
#include <cstddef>

typedef unsigned short u16;

#define HH 256
#define IIN 128
#define TT 512
#define G3 768

typedef __attribute__((ext_vector_type(8))) short bf16x8;
typedef __attribute__((ext_vector_type(4))) float f32x4;

__device__ __forceinline__ u16 f2bf(float f) {
    union { float f; uint32_t i; } c; c.f = f;
    uint32_t r = c.i + 0x7fffu + ((c.i >> 16) & 1u);
    return (u16)(r >> 16);
}
__device__ __forceinline__ float frcp(float x) { return __builtin_amdgcn_rcpf(x); }
__device__ __forceinline__ float sigm(float x) {
    float e = __expf(-fabsf(x));
    float s = frcp(1.f + e);
    return x >= 0.f ? s : 1.f - s;   // 1-s == e/(1+e)
}
__device__ __forceinline__ float tanh_f(float x) {
    float e = __expf(-2.f * fabsf(x));          // overflow-safe
    float t = (1.f - e) * frcp(1.f + e);
    return x >= 0.f ? t : -t;
}

// lgkmcnt-only barrier: drains LDS ops for cross-wave visibility but leaves
// global (vmcnt) loads in flight -- avoids the compiler's vmcnt(0) drain at
// __syncthreads that would serialize every recurrent step on HBM latency.
#define LDS_BARRIER() asm volatile("s_waitcnt lgkmcnt(0)\n\ts_barrier" ::: "memory")

// ---------------------------------------------------------------------------
// Kernel 1 (unchanged): xg[m][g] = x_row(m) . W_ih[g] + b_ih[g] + (g<512 ? b_hh[g] : 0)
// ---------------------------------------------------------------------------
__global__ __launch_bounds__(256, 2) void xg_gemm(
    const float* __restrict__ x, const float* __restrict__ W_ih,
    const float* __restrict__ b_ih, const float* __restrict__ b_hh,
    float* __restrict__ xg, int t0, int lt)
{
    __shared__ u16 xA[128 * 136];
    __shared__ u16 wB[128 * 136];
    __shared__ float biasS[128];
    const int tid = threadIdx.x;
    const int m0 = blockIdx.x * 128;
    const int TcM = (1 << lt) - 1;
    const int srow = tid >> 5, sc = (tid & 31) * 4;

    #pragma unroll
    for (int it = 0; it < 16; ++it) {
        int r = srow + it * 8;
        int row = m0 + r;
        int b = row >> lt;
        int t = t0 + (row & TcM);
        float4 xv = *(const float4*)(x + ((size_t)b * TT + t) * IIN + sc);
        ushort4 xs = { f2bf(xv.x), f2bf(xv.y), f2bf(xv.z), f2bf(xv.w) };
        *(ushort4*)&xA[r * 136 + sc] = xs;
    }

    const int lane = tid & 63, wv = tid >> 6;
    const int quad = lane >> 4, colL = lane & 15;

    #pragma unroll
    for (int nb = 0; nb < 2; ++nb) {
        const int n0 = blockIdx.y * 256 + nb * 128;
        if (nb) __syncthreads();
        #pragma unroll
        for (int it = 0; it < 16; ++it) {
            int r = srow + it * 8;
            float4 wv4 = *(const float4*)(W_ih + (size_t)(n0 + r) * IIN + sc);
            ushort4 ws4 = { f2bf(wv4.x), f2bf(wv4.y), f2bf(wv4.z), f2bf(wv4.w) };
            *(ushort4*)&wB[r * 136 + sc] = ws4;
        }
        if (tid < 128) {
            int n = n0 + tid;
            float bv = b_ih[n];
            if (n < 512) bv += b_hh[n];
            biasS[tid] = bv;
        }
        __syncthreads();

        f32x4 C[2][8] = {};
        #pragma unroll
        for (int kt = 0; kt < 4; ++kt) {
            bf16x8 A[2];
            #pragma unroll
            for (int i = 0; i < 2; ++i)
                A[i] = *(const bf16x8*)&xA[(wv * 32 + i * 16 + colL) * 136 + kt * 32 + quad * 8];
            #pragma unroll
            for (int nn = 0; nn < 8; ++nn) {
                bf16x8 Bf = *(const bf16x8*)&wB[(nn * 16 + colL) * 136 + kt * 32 + quad * 8];
                C[0][nn] = __builtin_amdgcn_mfma_f32_16x16x32_bf16(A[0], Bf, C[0][nn], 0, 0, 0);
                C[1][nn] = __builtin_amdgcn_mfma_f32_16x16x32_bf16(A[1], Bf, C[1][nn], 0, 0, 0);
            }
        }
        #pragma unroll
        for (int i = 0; i < 2; ++i)
            #pragma unroll
            for (int nn = 0; nn < 8; ++nn) {
                int c = nn * 16 + colL;
                float bv = biasS[c];
                #pragma unroll
                for (int r = 0; r < 4; ++r) {
                    int row = m0 + wv * 32 + i * 16 + quad * 4 + r;
                    xg[(size_t)row * G3 + n0 + c] = C[i][nn][r] + bv;
                }
            }
    }
}

// ---------------------------------------------------------------------------
// Kernel 2: persistent per-batch recurrence. grid=256 (1 WG/CU), block=512
// (8 waves, 2/SIMD). Wave wv owns hidden j in [32wv, 32wv+32) for all 3
// gates -> Bw[3][2][8] = 192 VGPRs of weights per lane: the FULL W_hh
// (384 KB bf16) fits in the block's register file (512 lanes x 192 x 4B)
// with no spilling (the 256-thread version needed 384 VGPRs/lane -> scratch
// spill reload every step was the bottleneck).
//
// Broadcast-A trick: ALL lanes load the same h-fragment (per-quad address ->
// free LDS broadcast), so every A row is identical and every C row is
// identical. Thread at lane L then holds dot(col = L&15) of both 16-col
// tiles in its own C registers -> one v_cndmask per gate replaces the old
// stg[] LDS write + lgkmcnt + read round-trip. Lanes 32..63 duplicate
// lanes 0..31 for the gate math (harmless); stores are guarded to lane<32.
// ---------------------------------------------------------------------------
#define GRU_STEP(TC_, HBR_, HBW_, PR_, PZ_, PN_) do {                          \
    f32x4 C[3][2] = {};                                                        \
    _Pragma("unroll")                                                          \
    for (int kt = 0; kt < 8; ++kt) {                                           \
        bf16x8 A = *(const bf16x8*)&HBR_[kt * 32 + quad * 8];                  \
        _Pragma("unroll")                                                      \
        for (int g = 0; g < 3; ++g) {                                          \
            C[g][0] = __builtin_amdgcn_mfma_f32_16x16x32_bf16(                 \
                          A, Bw[g][0][kt], C[g][0], 0, 0, 0);                  \
            C[g][1] = __builtin_amdgcn_mfma_f32_16x16x32_bf16(                 \
                          A, Bw[g][1][kt], C[g][1], 0, 0, 0);                  \
        }                                                                      \
    }                                                                          \
    float dr = i16 ? C[0][1][0] : C[0][0][0];                                  \
    float dz = i16 ? C[1][1][0] : C[1][0][0];                                  \
    float dn = i16 ? C[2][1][0] : C[2][0][0];                                  \
    float xr = PR_, xz = PZ_, xn = PN_;                                        \
    int t2 = (TC_) + 2; if (t2 > Tc - 1) t2 = Tc - 1;                          \
    const float* p2 = xgb + (size_t)t2 * G3;                                   \
    PR_ = p2[j]; PZ_ = p2[256 + j]; PN_ = p2[512 + j];                         \
    float r = sigm(xr + dr);                                                   \
    float z = sigm(xz + dz);                                                   \
    float n = tanh_f(xn + r * (dn + bhn));                                     \
    hreg = n + z * (hreg - n);                                                 \
    if (lane < 32) {                                                           \
        HBW_[j] = f2bf(hreg);                                                  \
        outb[(size_t)(t0 + (TC_)) * HH + j] = hreg;                            \
    }                                                                          \
    LDS_BARRIER();                                                             \
} while (0)

__global__ __launch_bounds__(512, 2) void gru_seq(
    const float* __restrict__ W_hh, const float* __restrict__ b_hh,
    const float* __restrict__ xg, float* __restrict__ out,
    float* __restrict__ hstate, int t0, int Tc)
{
    __shared__ u16 hBuf[2][HH];     // h bf16, double-buffered (A-frag source)

    const int tid = threadIdx.x;
    const int lane = tid & 63, wv = tid >> 6;       // wv in [0,8)
    const int quad = lane >> 4, colL = lane & 15;
    const int i16 = quad & 1;                       // which 16-col tile
    const int j = wv * 32 + (lane & 31);            // hidden index this lane owns
    const int b = blockIdx.x;

    // persistent weight fragments: B[k][col]: col = colL ->
    // W_hh row (g*256 + wv*32 + i*16 + colL), k = kt*32 + quad*8 + e
    bf16x8 Bw[3][2][8];
    #pragma unroll
    for (int g = 0; g < 3; ++g)
        #pragma unroll
        for (int i = 0; i < 2; ++i) {
            const size_t rowb = (size_t)(g * 256 + wv * 32 + i * 16 + colL) * HH;
            #pragma unroll
            for (int kt = 0; kt < 8; ++kt) {
                float4 lo = *(const float4*)(W_hh + rowb + kt * 32 + quad * 8);
                float4 hi = *(const float4*)(W_hh + rowb + kt * 32 + quad * 8 + 4);
                union { bf16x8 v; u16 s[8]; } u;
                u.s[0] = f2bf(lo.x); u.s[1] = f2bf(lo.y);
                u.s[2] = f2bf(lo.z); u.s[3] = f2bf(lo.w);
                u.s[4] = f2bf(hi.x); u.s[5] = f2bf(hi.y);
                u.s[6] = f2bf(hi.z); u.s[7] = f2bf(hi.w);
                Bw[g][i][kt] = u.v;
            }
        }

    float hreg = (t0 == 0) ? 0.f : hstate[b * HH + j];
    if (lane < 32) hBuf[0][j] = f2bf(hreg);
    const float bhn = b_hh[512 + j];
    const float* xgb = xg + (size_t)b * Tc * G3;
    float* outb = out + (size_t)b * TT * HH;

    // 2-deep xg prefetch (upper half-wave duplicates lower -> same cachelines)
    float pr0 = xgb[j],      pz0 = xgb[256 + j],      pn0 = xgb[512 + j];
    float pr1 = xgb[G3 + j], pz1 = xgb[G3 + 256 + j], pn1 = xgb[G3 + 512 + j];
    __syncthreads();   // once: weight/h init visible

    for (int tc = 0; tc < Tc; tc += 2) {
        GRU_STEP(tc,     hBuf[0], hBuf[1], pr0, pz0, pn0);
        GRU_STEP(tc + 1, hBuf[1], hBuf[0], pr1, pz1, pn1);
    }

    if (t0 + Tc < TT && lane < 32)      // only needed across chunks
        hstate[b * HH + j] = hreg;
}

extern "C" void kernel_launch(void* const* d_in, const int* in_sizes, int n_in,
                              void* d_out, int out_size, void* d_ws, size_t ws_size,
                              hipStream_t stream) {
    const float* x    = (const float*)d_in[0];
    const float* W_ih = (const float*)d_in[1];
    const float* W_hh = (const float*)d_in[2];
    const float* b_ih = (const float*)d_in[3];
    const float* b_hh = (const float*)d_in[4];
    float* out = (float*)d_out;                    // fp32 output [B,T,H]

    float* hstate = (float*)d_ws;                  // 256*256 fp32 = 256 KB
    float* xg = (float*)((char*)d_ws + 262144);    // [256*Tc, 768] fp32
    size_t avail = ws_size > 262144 ? ws_size - 262144 : 0;

    int Tc = TT, lt = 9;                           // shrink chunk to fit ws
    while (Tc > 4 && (size_t)256 * Tc * G3 * 4 > avail) { Tc >>= 1; --lt; }

    for (int t0 = 0; t0 < TT; t0 += Tc) {
        xg_gemm<<<dim3(2 * Tc, G3 / 256), 256, 0, stream>>>(
            x, W_ih, b_ih, b_hh, xg, t0, lt);
        gru_seq<<<dim3(256), 512, 0, stream>>>(
            W_hh, b_hh, xg, out, hstate, t0, Tc);
    }
}

// Round 2
// 847.037 us; speedup vs baseline: 1.4546x; 1.0020x over previous
//
#include <hip/hip_runtime.h>
#include <cstdint>
#include <cstddef>

typedef unsigned short u16;

#define HH 256
#define IIN 128
#define TT 512
#define G3 768

typedef __attribute__((ext_vector_type(8))) short bf16x8;
typedef __attribute__((ext_vector_type(4))) float f32x4;

__device__ __forceinline__ u16 f2bf(float f) {
    union { float f; uint32_t i; } c; c.f = f;
    uint32_t r = c.i + 0x7fffu + ((c.i >> 16) & 1u);
    return (u16)(r >> 16);
}
__device__ __forceinline__ float frcp(float x) { return __builtin_amdgcn_rcpf(x); }
__device__ __forceinline__ float sigm(float x) {
    float e = __expf(-fabsf(x));
    float s = frcp(1.f + e);
    return x >= 0.f ? s : 1.f - s;   // 1-s == e/(1+e)
}
__device__ __forceinline__ float tanh_f(float x) {
    float e = __expf(-2.f * fabsf(x));          // overflow-safe
    float t = (1.f - e) * frcp(1.f + e);
    return x >= 0.f ? t : -t;
}

// lgkmcnt-only barrier: drains LDS ops for cross-wave visibility but leaves
// global (vmcnt) loads in flight -- avoids the compiler's vmcnt(0) drain at
// __syncthreads that would serialize every recurrent step on HBM latency.
#define LDS_BARRIER() asm volatile("s_waitcnt lgkmcnt(0)\n\ts_barrier" ::: "memory")

// ---------------------------------------------------------------------------
// Kernel 1 (unchanged): xg[m][g] = x_row(m) . W_ih[g] + b_ih[g] + (g<512 ? b_hh[g] : 0)
// ---------------------------------------------------------------------------
__global__ __launch_bounds__(256, 2) void xg_gemm(
    const float* __restrict__ x, const float* __restrict__ W_ih,
    const float* __restrict__ b_ih, const float* __restrict__ b_hh,
    float* __restrict__ xg, int t0, int lt)
{
    __shared__ u16 xA[128 * 136];
    __shared__ u16 wB[128 * 136];
    __shared__ float biasS[128];
    const int tid = threadIdx.x;
    const int m0 = blockIdx.x * 128;
    const int TcM = (1 << lt) - 1;
    const int srow = tid >> 5, sc = (tid & 31) * 4;

    #pragma unroll
    for (int it = 0; it < 16; ++it) {
        int r = srow + it * 8;
        int row = m0 + r;
        int b = row >> lt;
        int t = t0 + (row & TcM);
        float4 xv = *(const float4*)(x + ((size_t)b * TT + t) * IIN + sc);
        ushort4 xs = { f2bf(xv.x), f2bf(xv.y), f2bf(xv.z), f2bf(xv.w) };
        *(ushort4*)&xA[r * 136 + sc] = xs;
    }

    const int lane = tid & 63, wv = tid >> 6;
    const int quad = lane >> 4, colL = lane & 15;

    #pragma unroll
    for (int nb = 0; nb < 2; ++nb) {
        const int n0 = blockIdx.y * 256 + nb * 128;
        if (nb) __syncthreads();
        #pragma unroll
        for (int it = 0; it < 16; ++it) {
            int r = srow + it * 8;
            float4 wv4 = *(const float4*)(W_ih + (size_t)(n0 + r) * IIN + sc);
            ushort4 ws4 = { f2bf(wv4.x), f2bf(wv4.y), f2bf(wv4.z), f2bf(wv4.w) };
            *(ushort4*)&wB[r * 136 + sc] = ws4;
        }
        if (tid < 128) {
            int n = n0 + tid;
            float bv = b_ih[n];
            if (n < 512) bv += b_hh[n];
            biasS[tid] = bv;
        }
        __syncthreads();

        f32x4 C[2][8] = {};
        #pragma unroll
        for (int kt = 0; kt < 4; ++kt) {
            bf16x8 A[2];
            #pragma unroll
            for (int i = 0; i < 2; ++i)
                A[i] = *(const bf16x8*)&xA[(wv * 32 + i * 16 + colL) * 136 + kt * 32 + quad * 8];
            #pragma unroll
            for (int nn = 0; nn < 8; ++nn) {
                bf16x8 Bf = *(const bf16x8*)&wB[(nn * 16 + colL) * 136 + kt * 32 + quad * 8];
                C[0][nn] = __builtin_amdgcn_mfma_f32_16x16x32_bf16(A[0], Bf, C[0][nn], 0, 0, 0);
                C[1][nn] = __builtin_amdgcn_mfma_f32_16x16x32_bf16(A[1], Bf, C[1][nn], 0, 0, 0);
            }
        }
        #pragma unroll
        for (int i = 0; i < 2; ++i)
            #pragma unroll
            for (int nn = 0; nn < 8; ++nn) {
                int c = nn * 16 + colL;
                float bv = biasS[c];
                #pragma unroll
                for (int r = 0; r < 4; ++r) {
                    int row = m0 + wv * 32 + i * 16 + quad * 4 + r;
                    xg[(size_t)row * G3 + n0 + c] = C[i][nn][r] + bv;
                }
            }
    }
}

// ---------------------------------------------------------------------------
// Kernel 2: persistent per-batch recurrence. grid=256 (1 WG/CU), block=512
// (8 waves, 2/SIMD). Wave wv owns hidden j in [32wv, 32wv+32) for all 3
// gates -> Bw[3][2][8] = 192 VGPRs of weights per lane.
//
// __launch_bounds__(512, 1): the 2nd arg is min WORKGROUPS/CU (observed:
// (512,2) produced a 128-VGPR cap = 4 waves/SIMD budget, forcing ~120 regs
// of weight spill that dominated the step time). With 1 block/CU the cap is
// 256 VGPRs: Bw(192) + C(24) + A(4) + prefetch(6) + misc ~= 244 fits with
// NO spilling. grid=256 == CU count, so a second resident block could never
// be placed anyway.
//
// Broadcast-A trick: ALL lanes load the same h-fragment (per-quad address ->
// free LDS broadcast), so every A row is identical and every C row is
// identical. Thread at lane L holds dot(col = L&15) of both 16-col tiles in
// its own C registers -> one v_cndmask per gate replaces any LDS round-trip.
// Lanes 32..63 duplicate lanes 0..31 for the gate math; stores guarded.
// ---------------------------------------------------------------------------
#define GRU_STEP(TC_, HBR_, HBW_, PR_, PZ_, PN_) do {                          \
    f32x4 C[3][2] = {};                                                        \
    _Pragma("unroll")                                                          \
    for (int kt = 0; kt < 8; ++kt) {                                           \
        bf16x8 A = *(const bf16x8*)&HBR_[kt * 32 + quad * 8];                  \
        _Pragma("unroll")                                                      \
        for (int g = 0; g < 3; ++g) {                                          \
            C[g][0] = __builtin_amdgcn_mfma_f32_16x16x32_bf16(                 \
                          A, Bw[g][0][kt], C[g][0], 0, 0, 0);                  \
            C[g][1] = __builtin_amdgcn_mfma_f32_16x16x32_bf16(                 \
                          A, Bw[g][1][kt], C[g][1], 0, 0, 0);                  \
        }                                                                      \
    }                                                                          \
    float dr = i16 ? C[0][1][0] : C[0][0][0];                                  \
    float dz = i16 ? C[1][1][0] : C[1][0][0];                                  \
    float dn = i16 ? C[2][1][0] : C[2][0][0];                                  \
    float xr = PR_, xz = PZ_, xn = PN_;                                        \
    int t2 = (TC_) + 2; if (t2 > Tc - 1) t2 = Tc - 1;                          \
    const float* p2 = xgb + (size_t)t2 * G3;                                   \
    PR_ = p2[j]; PZ_ = p2[256 + j]; PN_ = p2[512 + j];                         \
    float r = sigm(xr + dr);                                                   \
    float z = sigm(xz + dz);                                                   \
    float n = tanh_f(xn + r * (dn + bhn));                                     \
    hreg = n + z * (hreg - n);                                                 \
    if (lane < 32) {                                                           \
        HBW_[j] = f2bf(hreg);                                                  \
        outb[(size_t)(t0 + (TC_)) * HH + j] = hreg;                            \
    }                                                                          \
    LDS_BARRIER();                                                             \
} while (0)

__global__ __launch_bounds__(512, 1) void gru_seq(
    const float* __restrict__ W_hh, const float* __restrict__ b_hh,
    const float* __restrict__ xg, float* __restrict__ out,
    float* __restrict__ hstate, int t0, int Tc)
{
    __shared__ u16 hBuf[2][HH];     // h bf16, double-buffered (A-frag source)

    const int tid = threadIdx.x;
    const int lane = tid & 63, wv = tid >> 6;       // wv in [0,8)
    const int quad = lane >> 4, colL = lane & 15;
    const int i16 = quad & 1;                       // which 16-col tile
    const int j = wv * 32 + (lane & 31);            // hidden index this lane owns
    const int b = blockIdx.x;

    // persistent weight fragments: B[k][col]: col = colL ->
    // W_hh row (g*256 + wv*32 + i*16 + colL), k = kt*32 + quad*8 + e
    bf16x8 Bw[3][2][8];
    #pragma unroll
    for (int g = 0; g < 3; ++g)
        #pragma unroll
        for (int i = 0; i < 2; ++i) {
            const size_t rowb = (size_t)(g * 256 + wv * 32 + i * 16 + colL) * HH;
            #pragma unroll
            for (int kt = 0; kt < 8; ++kt) {
                float4 lo = *(const float4*)(W_hh + rowb + kt * 32 + quad * 8);
                float4 hi = *(const float4*)(W_hh + rowb + kt * 32 + quad * 8 + 4);
                union { bf16x8 v; u16 s[8]; } u;
                u.s[0] = f2bf(lo.x); u.s[1] = f2bf(lo.y);
                u.s[2] = f2bf(lo.z); u.s[3] = f2bf(lo.w);
                u.s[4] = f2bf(hi.x); u.s[5] = f2bf(hi.y);
                u.s[6] = f2bf(hi.z); u.s[7] = f2bf(hi.w);
                Bw[g][i][kt] = u.v;
            }
        }

    float hreg = (t0 == 0) ? 0.f : hstate[b * HH + j];
    if (lane < 32) hBuf[0][j] = f2bf(hreg);
    const float bhn = b_hh[512 + j];
    const float* xgb = xg + (size_t)b * Tc * G3;
    float* outb = out + (size_t)b * TT * HH;

    // 2-deep xg prefetch (upper half-wave duplicates lower -> same cachelines)
    float pr0 = xgb[j],      pz0 = xgb[256 + j],      pn0 = xgb[512 + j];
    float pr1 = xgb[G3 + j], pz1 = xgb[G3 + 256 + j], pn1 = xgb[G3 + 512 + j];
    __syncthreads();   // once: weight/h init visible

    for (int tc = 0; tc < Tc; tc += 2) {
        GRU_STEP(tc,     hBuf[0], hBuf[1], pr0, pz0, pn0);
        GRU_STEP(tc + 1, hBuf[1], hBuf[0], pr1, pz1, pn1);
    }

    if (t0 + Tc < TT && lane < 32)      // only needed across chunks
        hstate[b * HH + j] = hreg;
}

extern "C" void kernel_launch(void* const* d_in, const int* in_sizes, int n_in,
                              void* d_out, int out_size, void* d_ws, size_t ws_size,
                              hipStream_t stream) {
    const float* x    = (const float*)d_in[0];
    const float* W_ih = (const float*)d_in[1];
    const float* W_hh = (const float*)d_in[2];
    const float* b_ih = (const float*)d_in[3];
    const float* b_hh = (const float*)d_in[4];
    float* out = (float*)d_out;                    // fp32 output [B,T,H]

    float* hstate = (float*)d_ws;                  // 256*256 fp32 = 256 KB
    float* xg = (float*)((char*)d_ws + 262144);    // [256*Tc, 768] fp32
    size_t avail = ws_size > 262144 ? ws_size - 262144 : 0;

    int Tc = TT, lt = 9;                           // shrink chunk to fit ws
    while (Tc > 4 && (size_t)256 * Tc * G3 * 4 > avail) { Tc >>= 1; --lt; }

    for (int t0 = 0; t0 < TT; t0 += Tc) {
        xg_gemm<<<dim3(2 * Tc, G3 / 256), 256, 0, stream>>>(
            x, W_ih, b_ih, b_hh, xg, t0, lt);
        gru_seq<<<dim3(256), 512, 0, stream>>>(
            W_hh, b_hh, xg, out, hstate, t0, Tc);
    }
}

// Round 3
// 710.720 us; speedup vs baseline: 1.7335x; 1.1918x over previous
//
#include <hip/hip_runtime.h>
#include <cstdint>
#include <cstddef>

typedef unsigned short u16;

#define HH 256
#define IIN 128
#define TT 512
#define G3 768

typedef __attribute__((ext_vector_type(8))) short bf16x8;
typedef __attribute__((ext_vector_type(4))) float f32x4;
typedef __attribute__((ext_vector_type(4))) int   i32x4;

__device__ __forceinline__ u16 f2bf(float f) {
    union { float f; uint32_t i; } c; c.f = f;
    uint32_t r = c.i + 0x7fffu + ((c.i >> 16) & 1u);
    return (u16)(r >> 16);
}
__device__ __forceinline__ float bf2f(u16 s) {
    union { uint32_t i; float f; } u; u.i = ((uint32_t)s) << 16; return u.f;
}
__device__ __forceinline__ float frcp(float x) { return __builtin_amdgcn_rcpf(x); }
__device__ __forceinline__ float sigm(float x) {
    float e = __expf(-fabsf(x));
    float s = frcp(1.f + e);
    return x >= 0.f ? s : 1.f - s;   // 1-s == e/(1+e)
}
__device__ __forceinline__ float tanh_f(float x) {
    float e = __expf(-2.f * fabsf(x));          // overflow-safe
    float t = (1.f - e) * frcp(1.f + e);
    return x >= 0.f ? t : -t;
}

// lgkmcnt-only barrier: drains LDS ops for cross-wave visibility but leaves
// global (vmcnt) loads in flight.
#define LDS_BARRIER() asm volatile("s_waitcnt lgkmcnt(0)\n\ts_barrier" ::: "memory")

// ---------------------------------------------------------------------------
// Kernel 1: xg[m][g] = x_row(m) . W_ih[g] + b_ih[g] + (g<512 ? b_hh[g] : 0)
// Output now BF16 (halves the 402 MB xg write + gru-side fetch).
// ---------------------------------------------------------------------------
__global__ __launch_bounds__(256, 2) void xg_gemm(
    const float* __restrict__ x, const float* __restrict__ W_ih,
    const float* __restrict__ b_ih, const float* __restrict__ b_hh,
    u16* __restrict__ xg, int t0, int lt)
{
    __shared__ u16 xA[128 * 136];
    __shared__ u16 wB[128 * 136];
    __shared__ float biasS[128];
    const int tid = threadIdx.x;
    const int m0 = blockIdx.x * 128;
    const int TcM = (1 << lt) - 1;
    const int srow = tid >> 5, sc = (tid & 31) * 4;

    #pragma unroll
    for (int it = 0; it < 16; ++it) {
        int r = srow + it * 8;
        int row = m0 + r;
        int b = row >> lt;
        int t = t0 + (row & TcM);
        float4 xv = *(const float4*)(x + ((size_t)b * TT + t) * IIN + sc);
        ushort4 xs = { f2bf(xv.x), f2bf(xv.y), f2bf(xv.z), f2bf(xv.w) };
        *(ushort4*)&xA[r * 136 + sc] = xs;
    }

    const int lane = tid & 63, wv = tid >> 6;
    const int quad = lane >> 4, colL = lane & 15;

    #pragma unroll
    for (int nb = 0; nb < 2; ++nb) {
        const int n0 = blockIdx.y * 256 + nb * 128;
        if (nb) __syncthreads();
        #pragma unroll
        for (int it = 0; it < 16; ++it) {
            int r = srow + it * 8;
            float4 wv4 = *(const float4*)(W_ih + (size_t)(n0 + r) * IIN + sc);
            ushort4 ws4 = { f2bf(wv4.x), f2bf(wv4.y), f2bf(wv4.z), f2bf(wv4.w) };
            *(ushort4*)&wB[r * 136 + sc] = ws4;
        }
        if (tid < 128) {
            int n = n0 + tid;
            float bv = b_ih[n];
            if (n < 512) bv += b_hh[n];
            biasS[tid] = bv;
        }
        __syncthreads();

        f32x4 C[2][8] = {};
        #pragma unroll
        for (int kt = 0; kt < 4; ++kt) {
            bf16x8 A[2];
            #pragma unroll
            for (int i = 0; i < 2; ++i)
                A[i] = *(const bf16x8*)&xA[(wv * 32 + i * 16 + colL) * 136 + kt * 32 + quad * 8];
            #pragma unroll
            for (int nn = 0; nn < 8; ++nn) {
                bf16x8 Bf = *(const bf16x8*)&wB[(nn * 16 + colL) * 136 + kt * 32 + quad * 8];
                C[0][nn] = __builtin_amdgcn_mfma_f32_16x16x32_bf16(A[0], Bf, C[0][nn], 0, 0, 0);
                C[1][nn] = __builtin_amdgcn_mfma_f32_16x16x32_bf16(A[1], Bf, C[1][nn], 0, 0, 0);
            }
        }
        #pragma unroll
        for (int i = 0; i < 2; ++i)
            #pragma unroll
            for (int nn = 0; nn < 8; ++nn) {
                int c = nn * 16 + colL;
                float bv = biasS[c];
                #pragma unroll
                for (int r = 0; r < 4; ++r) {
                    int row = m0 + wv * 32 + i * 16 + quad * 4 + r;
                    xg[(size_t)row * G3 + n0 + c] = f2bf(C[i][nn][r] + bv);
                }
            }
    }
}

// ---------------------------------------------------------------------------
// Kernel 2: persistent per-batch recurrence. grid=256, block=512 (8 waves,
// 2/SIMD). The step is MFMA-issue-bound (384 bf16 MFMAs/CU/step = 1862 cyc,
// matched MfmaUtil 56%). Reduce cycles-per-N.K with i8 K=64 MFMAs for the
// r,z gates (sigmoid slope <=0.25 damps quant noise); keep the n gate
// (integrator) in bf16:
//   rz: 16 i8 MFMA/wave (K=64) + n: 16 bf16 MFMA/wave  -> ~1274 cyc/CU/step.
// Weights: rz as per-row-scaled int8 (64 VGPR), n as bf16 (64 VGPR) = 128
// total (was 192) -> register pressure relief on the 256/wave budget.
// Broadcast-A: all lanes read the same h fragment -> all C rows identical,
// so lane L holds the dot for col L&15 in C[..][0]; i16 selects the tile.
// k-permutation safety: A and B are loaded with the same (quad,byte)->k
// formula, so any internal k ordering cancels in the dot product.
// ---------------------------------------------------------------------------
#define GRU_STEP(TC_, HBR_, HBW_, HQR_, HQW_, PR_, PZ_, PN_) do {              \
    f32x4 Cn[2] = {};                                                          \
    i32x4 Cr[2] = {}, Cz[2] = {};                                              \
    _Pragma("unroll")                                                          \
    for (int kt = 0; kt < 4; ++kt) {                                           \
        i32x4 Aq = *(const i32x4*)((const char*)(HQR_) + kt * 64 + quad * 16); \
        Cr[0] = __builtin_amdgcn_mfma_i32_16x16x64_i8(Aq, Br[0][kt], Cr[0], 0, 0, 0); \
        Cr[1] = __builtin_amdgcn_mfma_i32_16x16x64_i8(Aq, Br[1][kt], Cr[1], 0, 0, 0); \
        Cz[0] = __builtin_amdgcn_mfma_i32_16x16x64_i8(Aq, Bz[0][kt], Cz[0], 0, 0, 0); \
        Cz[1] = __builtin_amdgcn_mfma_i32_16x16x64_i8(Aq, Bz[1][kt], Cz[1], 0, 0, 0); \
    }                                                                          \
    _Pragma("unroll")                                                          \
    for (int kt = 0; kt < 8; ++kt) {                                           \
        bf16x8 A = *(const bf16x8*)&HBR_[kt * 32 + quad * 8];                  \
        Cn[0] = __builtin_amdgcn_mfma_f32_16x16x32_bf16(A, Bn[0][kt], Cn[0], 0, 0, 0); \
        Cn[1] = __builtin_amdgcn_mfma_f32_16x16x32_bf16(A, Bn[1][kt], Cn[1], 0, 0, 0); \
    }                                                                          \
    float dr = (float)(i16 ? Cr[1][0] : Cr[0][0]) * scR;                       \
    float dz = (float)(i16 ? Cz[1][0] : Cz[0][0]) * scZ;                       \
    float dn = i16 ? Cn[1][0] : Cn[0][0];                                      \
    float xr = PR_, xz = PZ_, xn = PN_;                                        \
    int t2 = (TC_) + 2; if (t2 > Tc - 1) t2 = Tc - 1;                          \
    const u16* p2 = xgb + (size_t)t2 * G3;                                     \
    PR_ = bf2f(p2[j]); PZ_ = bf2f(p2[256 + j]); PN_ = bf2f(p2[512 + j]);       \
    float r = sigm(xr + dr);                                                   \
    float z = sigm(xz + dz);                                                   \
    float n = tanh_f(xn + r * (dn + bhn));                                     \
    hreg = n + z * (hreg - n);                                                 \
    float hc = fminf(fmaxf(hreg, -1.f), 1.f);   /* |h|<=1 mathematically */    \
    int hq8 = (int)rintf(hc * 127.f);                                          \
    if (lane < 32) {                                                           \
        HBW_[j] = f2bf(hreg);                                                  \
        ((char*)(HQW_))[j] = (char)hq8;                                        \
        outb[(size_t)(t0 + (TC_)) * HH + j] = hreg;                            \
    }                                                                          \
    LDS_BARRIER();                                                             \
} while (0)

__global__ __launch_bounds__(512, 1) void gru_seq(
    const float* __restrict__ W_hh, const float* __restrict__ b_hh,
    const u16* __restrict__ xg, float* __restrict__ out,
    float* __restrict__ hstate, int t0, int Tc)
{
    __shared__ __align__(16) u16 hBuf[2][HH];   // h bf16, double-buffered (n gate)
    __shared__ __align__(16) int hqBuf[2][HH / 4]; // h int8 (*127), double-buffered (r,z)

    const int tid = threadIdx.x;
    const int lane = tid & 63, wv = tid >> 6;       // wv in [0,8)
    const int quad = lane >> 4, colL = lane & 15;
    const int i16 = quad & 1;                       // which 16-col tile
    const int j = wv * 32 + (lane & 31);            // hidden index this lane owns
    const int b = blockIdx.x;

    // ---- n-gate weights: bf16 fragments (rows 512..767) ----
    bf16x8 Bn[2][8];
    #pragma unroll
    for (int i = 0; i < 2; ++i) {
        const size_t rowb = (size_t)(512 + wv * 32 + i * 16 + colL) * HH;
        #pragma unroll
        for (int kt = 0; kt < 8; ++kt) {
            float4 lo = *(const float4*)(W_hh + rowb + kt * 32 + quad * 8);
            float4 hi = *(const float4*)(W_hh + rowb + kt * 32 + quad * 8 + 4);
            union { bf16x8 v; u16 s[8]; } u;
            u.s[0] = f2bf(lo.x); u.s[1] = f2bf(lo.y);
            u.s[2] = f2bf(lo.z); u.s[3] = f2bf(lo.w);
            u.s[4] = f2bf(hi.x); u.s[5] = f2bf(hi.y);
            u.s[6] = f2bf(hi.z); u.s[7] = f2bf(hi.w);
            Bn[i][kt] = u.v;
        }
    }

    // ---- r,z weights: per-row-scaled int8, packed 16 bytes/frag ----
    // frag byte (quad,u*4+e) holds W[row][kt*64 + quad*16 + u*4+e] * 127/rowmax
    i32x4 Br[2][4], Bz[2][4];
    float scR = 0.f, scZ = 0.f;     // combined dequant scale rowmax/(127*127)
    #pragma unroll
    for (int g = 0; g < 2; ++g) {
        #pragma unroll
        for (int i = 0; i < 2; ++i) {
            const float* wr = W_hh + (size_t)(g * 256 + wv * 32 + i * 16 + colL) * HH;
            float m = 0.f;
            #pragma unroll
            for (int kt = 0; kt < 4; ++kt)
                #pragma unroll
                for (int u4 = 0; u4 < 4; ++u4) {
                    float4 v = *(const float4*)(wr + kt * 64 + quad * 16 + u4 * 4);
                    m = fmaxf(m, fmaxf(fmaxf(fabsf(v.x), fabsf(v.y)),
                                       fmaxf(fabsf(v.z), fabsf(v.w))));
                }
            m = fmaxf(m, __shfl_xor(m, 16));    // full row spans all 4 quads
            m = fmaxf(m, __shfl_xor(m, 32));
            float inv = m > 1e-30f ? 127.f / m : 0.f;
            float sc  = m * (1.f / 16129.f);
            #pragma unroll
            for (int kt = 0; kt < 4; ++kt) {
                int pk[4];
                #pragma unroll
                for (int u4 = 0; u4 < 4; ++u4) {
                    float4 v = *(const float4*)(wr + kt * 64 + quad * 16 + u4 * 4);
                    int q0 = (int)rintf(fminf(fmaxf(v.x * inv, -127.f), 127.f));
                    int q1 = (int)rintf(fminf(fmaxf(v.y * inv, -127.f), 127.f));
                    int q2 = (int)rintf(fminf(fmaxf(v.z * inv, -127.f), 127.f));
                    int q3 = (int)rintf(fminf(fmaxf(v.w * inv, -127.f), 127.f));
                    pk[u4] = (q0 & 255) | ((q1 & 255) << 8) | ((q2 & 255) << 16) | (q3 << 24);
                }
                i32x4 t = { pk[0], pk[1], pk[2], pk[3] };
                if (g == 0) Br[i][kt] = t; else Bz[i][kt] = t;
            }
            if (i == i16) { if (g == 0) scR = sc; else scZ = sc; }
        }
    }

    float hreg = (t0 == 0) ? 0.f : hstate[b * HH + j];
    if (lane < 32) {
        hBuf[0][j] = f2bf(hreg);
        float hc = fminf(fmaxf(hreg, -1.f), 1.f);
        ((char*)hqBuf[0])[j] = (char)(int)rintf(hc * 127.f);
    }
    const float bhn = b_hh[512 + j];
    const u16* xgb = xg + (size_t)b * Tc * G3;
    float* outb = out + (size_t)b * TT * HH;

    // 2-deep xg prefetch (upper half-wave duplicates lower -> same cachelines)
    float pr0 = bf2f(xgb[j]),      pz0 = bf2f(xgb[256 + j]),      pn0 = bf2f(xgb[512 + j]);
    float pr1 = bf2f(xgb[G3 + j]), pz1 = bf2f(xgb[G3 + 256 + j]), pn1 = bf2f(xgb[G3 + 512 + j]);
    __syncthreads();   // once: weight/h init visible

    for (int tc = 0; tc < Tc; tc += 2) {
        GRU_STEP(tc,     hBuf[0], hBuf[1], hqBuf[0], hqBuf[1], pr0, pz0, pn0);
        GRU_STEP(tc + 1, hBuf[1], hBuf[0], hqBuf[1], hqBuf[0], pr1, pz1, pn1);
    }

    if (t0 + Tc < TT && lane < 32)      // only needed across chunks
        hstate[b * HH + j] = hreg;
}

extern "C" void kernel_launch(void* const* d_in, const int* in_sizes, int n_in,
                              void* d_out, int out_size, void* d_ws, size_t ws_size,
                              hipStream_t stream) {
    const float* x    = (const float*)d_in[0];
    const float* W_ih = (const float*)d_in[1];
    const float* W_hh = (const float*)d_in[2];
    const float* b_ih = (const float*)d_in[3];
    const float* b_hh = (const float*)d_in[4];
    float* out = (float*)d_out;                    // fp32 output [B,T,H]

    float* hstate = (float*)d_ws;                  // 256*256 fp32 = 256 KB
    u16* xg = (u16*)((char*)d_ws + 262144);        // [256*Tc, 768] bf16
    size_t avail = ws_size > 262144 ? ws_size - 262144 : 0;

    int Tc = TT, lt = 9;                           // shrink chunk to fit ws
    while (Tc > 4 && (size_t)256 * Tc * G3 * 2 > avail) { Tc >>= 1; --lt; }

    for (int t0 = 0; t0 < TT; t0 += Tc) {
        xg_gemm<<<dim3(2 * Tc, G3 / 256), 256, 0, stream>>>(
            x, W_ih, b_ih, b_hh, xg, t0, lt);
        gru_seq<<<dim3(256), 512, 0, stream>>>(
            W_hh, b_hh, xg, out, hstate, t0, Tc);
    }
}

// Round 4
// 698.982 us; speedup vs baseline: 1.7627x; 1.0168x over previous
//
#include <hip/hip_runtime.h>
#include <cstdint>
#include <cstddef>

typedef unsigned short u16;

#define HH 256
#define IIN 128
#define TT 512
#define G3 768

typedef __attribute__((ext_vector_type(8))) short bf16x8;
typedef __attribute__((ext_vector_type(4))) float f32x4;
typedef __attribute__((ext_vector_type(4))) int   i32x4;

__device__ __forceinline__ u16 f2bf(float f) {
    union { float f; uint32_t i; } c; c.f = f;
    uint32_t r = c.i + 0x7fffu + ((c.i >> 16) & 1u);
    return (u16)(r >> 16);
}
__device__ __forceinline__ float bf2f(u16 s) {
    union { uint32_t i; float f; } u; u.i = ((uint32_t)s) << 16; return u.f;
}
__device__ __forceinline__ float frcp(float x) { return __builtin_amdgcn_rcpf(x); }
__device__ __forceinline__ float sigm(float x) {
    float e = __expf(-fabsf(x));
    float s = frcp(1.f + e);
    return x >= 0.f ? s : 1.f - s;   // 1-s == e/(1+e)
}
__device__ __forceinline__ float tanh_f(float x) {
    float e = __expf(-2.f * fabsf(x));          // overflow-safe
    float t = (1.f - e) * frcp(1.f + e);
    return x >= 0.f ? t : -t;
}

// lgkmcnt-only barrier: drains LDS ops for cross-wave visibility but leaves
// global (vmcnt) loads in flight.
#define LDS_BARRIER() asm volatile("s_waitcnt lgkmcnt(0)\n\ts_barrier" ::: "memory")

// ---------------------------------------------------------------------------
// Kernel 1 v2: xg[m][g] = x_row(m) . W_ih[g] + b_ih[g] + (g<512 ? b_hh[g] : 0)
// Old version staged W_ih per 128-row block: 3072 blocks x 128KB = 400 MB of
// W reads (the dominant traffic; ~185 us vs a 43 us floor). Now: grid
// (Tc/4, 2); each block stages its THREE 128-col W-tiles (104 KB LDS) ONCE
// and loops 8 x-tiles of 128 rows over them. W traffic 400 -> 49 MB, x read
// 2 passes (2nd L3-hit), write unchanged. LDS 140.8 KB -> 1 block/CU, 256
// blocks = 256 CUs.
// ---------------------------------------------------------------------------
__global__ __launch_bounds__(256, 1) void xg_gemm(
    const float* __restrict__ x, const float* __restrict__ W_ih,
    const float* __restrict__ b_ih, const float* __restrict__ b_hh,
    u16* __restrict__ xg, int t0, int lt)
{
    // stride 136 u16 = 272B (odd multiple of 16B) -> conflict-free b128 reads
    __shared__ u16 xA[128 * 136];
    __shared__ u16 wB[3][128 * 136];
    __shared__ float biasS[384];
    const int tid = threadIdx.x;
    const int TcM = (1 << lt) - 1;
    const int srow = tid >> 5, sc = (tid & 31) * 4;
    const int lane = tid & 63, wv = tid >> 6;
    const int quad = lane >> 4, colL = lane & 15;

    // ---- stage 3 W-tiles (384 cols of this by) once ----
    #pragma unroll
    for (int w3 = 0; w3 < 3; ++w3) {
        const int n0 = blockIdx.y * 384 + w3 * 128;
        #pragma unroll
        for (int it = 0; it < 16; ++it) {
            int r = srow + it * 8;
            float4 wv4 = *(const float4*)(W_ih + (size_t)(n0 + r) * IIN + sc);
            ushort4 ws4 = { f2bf(wv4.x), f2bf(wv4.y), f2bf(wv4.z), f2bf(wv4.w) };
            *(ushort4*)&wB[w3][r * 136 + sc] = ws4;
        }
    }
    for (int n = tid; n < 384; n += 256) {
        int g = blockIdx.y * 384 + n;
        float bv = b_ih[g];
        if (g < 512) bv += b_hh[g];     // fold b_hh into r,z pre-activations
        biasS[n] = bv;
    }

    // ---- loop 8 x-tiles of 128 rows ----
    for (int xt = 0; xt < 8; ++xt) {
        const int m0 = blockIdx.x * 1024 + xt * 128;
        if (xt) __syncthreads();        // waves done reading previous xA
        #pragma unroll
        for (int it = 0; it < 16; ++it) {
            int r = srow + it * 8;
            int row = m0 + r;
            int b = row >> lt;
            int t = t0 + (row & TcM);
            float4 xv = *(const float4*)(x + ((size_t)b * TT + t) * IIN + sc);
            ushort4 xs = { f2bf(xv.x), f2bf(xv.y), f2bf(xv.z), f2bf(xv.w) };
            *(ushort4*)&xA[r * 136 + sc] = xs;
        }
        __syncthreads();

        #pragma unroll
        for (int w3 = 0; w3 < 3; ++w3) {
            f32x4 C[2][8] = {};
            #pragma unroll
            for (int kt = 0; kt < 4; ++kt) {
                bf16x8 A[2];
                #pragma unroll
                for (int i = 0; i < 2; ++i)
                    A[i] = *(const bf16x8*)&xA[(wv * 32 + i * 16 + colL) * 136 + kt * 32 + quad * 8];
                #pragma unroll
                for (int nn = 0; nn < 8; ++nn) {
                    bf16x8 Bf = *(const bf16x8*)&wB[w3][(nn * 16 + colL) * 136 + kt * 32 + quad * 8];
                    C[0][nn] = __builtin_amdgcn_mfma_f32_16x16x32_bf16(A[0], Bf, C[0][nn], 0, 0, 0);
                    C[1][nn] = __builtin_amdgcn_mfma_f32_16x16x32_bf16(A[1], Bf, C[1][nn], 0, 0, 0);
                }
            }
            // C layout [m89]: row = quad*4 + reg, col = lane&15
            #pragma unroll
            for (int i = 0; i < 2; ++i)
                #pragma unroll
                for (int nn = 0; nn < 8; ++nn) {
                    int cl = w3 * 128 + nn * 16 + colL;
                    float bv = biasS[cl];
                    #pragma unroll
                    for (int r = 0; r < 4; ++r) {
                        int row = m0 + wv * 32 + i * 16 + quad * 4 + r;
                        xg[(size_t)row * G3 + blockIdx.y * 384 + cl] = f2bf(C[i][nn][r] + bv);
                    }
                }
        }
    }
}

// ---------------------------------------------------------------------------
// Kernel 2 (unchanged from round 3, passed @522us): persistent per-batch
// recurrence. grid=256, block=512 (8 waves, 2/SIMD). i8 K=64 MFMAs for r,z
// (sigmoid slope <=0.25 damps quant noise); n gate (integrator) in bf16.
// Per-CU MFMA floor ~1274 cyc/step; measured 2447 -> tail is the next lever.
// ---------------------------------------------------------------------------
#define GRU_STEP(TC_, HBR_, HBW_, HQR_, HQW_, PR_, PZ_, PN_) do {              \
    f32x4 Cn[2] = {};                                                          \
    i32x4 Cr[2] = {}, Cz[2] = {};                                              \
    _Pragma("unroll")                                                          \
    for (int kt = 0; kt < 4; ++kt) {                                           \
        i32x4 Aq = *(const i32x4*)((const char*)(HQR_) + kt * 64 + quad * 16); \
        Cr[0] = __builtin_amdgcn_mfma_i32_16x16x64_i8(Aq, Br[0][kt], Cr[0], 0, 0, 0); \
        Cr[1] = __builtin_amdgcn_mfma_i32_16x16x64_i8(Aq, Br[1][kt], Cr[1], 0, 0, 0); \
        Cz[0] = __builtin_amdgcn_mfma_i32_16x16x64_i8(Aq, Bz[0][kt], Cz[0], 0, 0, 0); \
        Cz[1] = __builtin_amdgcn_mfma_i32_16x16x64_i8(Aq, Bz[1][kt], Cz[1], 0, 0, 0); \
    }                                                                          \
    _Pragma("unroll")                                                          \
    for (int kt = 0; kt < 8; ++kt) {                                           \
        bf16x8 A = *(const bf16x8*)&HBR_[kt * 32 + quad * 8];                  \
        Cn[0] = __builtin_amdgcn_mfma_f32_16x16x32_bf16(A, Bn[0][kt], Cn[0], 0, 0, 0); \
        Cn[1] = __builtin_amdgcn_mfma_f32_16x16x32_bf16(A, Bn[1][kt], Cn[1], 0, 0, 0); \
    }                                                                          \
    float dr = (float)(i16 ? Cr[1][0] : Cr[0][0]) * scR;                       \
    float dz = (float)(i16 ? Cz[1][0] : Cz[0][0]) * scZ;                       \
    float dn = i16 ? Cn[1][0] : Cn[0][0];                                      \
    float xr = PR_, xz = PZ_, xn = PN_;                                        \
    int t2 = (TC_) + 2; if (t2 > Tc - 1) t2 = Tc - 1;                          \
    const u16* p2 = xgb + (size_t)t2 * G3;                                     \
    PR_ = bf2f(p2[j]); PZ_ = bf2f(p2[256 + j]); PN_ = bf2f(p2[512 + j]);       \
    float r = sigm(xr + dr);                                                   \
    float z = sigm(xz + dz);                                                   \
    float n = tanh_f(xn + r * (dn + bhn));                                     \
    hreg = n + z * (hreg - n);                                                 \
    float hc = fminf(fmaxf(hreg, -1.f), 1.f);   /* |h|<=1 mathematically */    \
    int hq8 = (int)rintf(hc * 127.f);                                          \
    if (lane < 32) {                                                           \
        HBW_[j] = f2bf(hreg);                                                  \
        ((char*)(HQW_))[j] = (char)hq8;                                        \
        outb[(size_t)(t0 + (TC_)) * HH + j] = hreg;                            \
    }                                                                          \
    LDS_BARRIER();                                                             \
} while (0)

__global__ __launch_bounds__(512, 1) void gru_seq(
    const float* __restrict__ W_hh, const float* __restrict__ b_hh,
    const u16* __restrict__ xg, float* __restrict__ out,
    float* __restrict__ hstate, int t0, int Tc)
{
    __shared__ __align__(16) u16 hBuf[2][HH];   // h bf16, double-buffered (n gate)
    __shared__ __align__(16) int hqBuf[2][HH / 4]; // h int8 (*127), double-buffered (r,z)

    const int tid = threadIdx.x;
    const int lane = tid & 63, wv = tid >> 6;       // wv in [0,8)
    const int quad = lane >> 4, colL = lane & 15;
    const int i16 = quad & 1;                       // which 16-col tile
    const int j = wv * 32 + (lane & 31);            // hidden index this lane owns
    const int b = blockIdx.x;

    // ---- n-gate weights: bf16 fragments (rows 512..767) ----
    bf16x8 Bn[2][8];
    #pragma unroll
    for (int i = 0; i < 2; ++i) {
        const size_t rowb = (size_t)(512 + wv * 32 + i * 16 + colL) * HH;
        #pragma unroll
        for (int kt = 0; kt < 8; ++kt) {
            float4 lo = *(const float4*)(W_hh + rowb + kt * 32 + quad * 8);
            float4 hi = *(const float4*)(W_hh + rowb + kt * 32 + quad * 8 + 4);
            union { bf16x8 v; u16 s[8]; } u;
            u.s[0] = f2bf(lo.x); u.s[1] = f2bf(lo.y);
            u.s[2] = f2bf(lo.z); u.s[3] = f2bf(lo.w);
            u.s[4] = f2bf(hi.x); u.s[5] = f2bf(hi.y);
            u.s[6] = f2bf(hi.z); u.s[7] = f2bf(hi.w);
            Bn[i][kt] = u.v;
        }
    }

    // ---- r,z weights: per-row-scaled int8, packed 16 bytes/frag ----
    i32x4 Br[2][4], Bz[2][4];
    float scR = 0.f, scZ = 0.f;     // combined dequant scale rowmax/(127*127)
    #pragma unroll
    for (int g = 0; g < 2; ++g) {
        #pragma unroll
        for (int i = 0; i < 2; ++i) {
            const float* wr = W_hh + (size_t)(g * 256 + wv * 32 + i * 16 + colL) * HH;
            float m = 0.f;
            #pragma unroll
            for (int kt = 0; kt < 4; ++kt)
                #pragma unroll
                for (int u4 = 0; u4 < 4; ++u4) {
                    float4 v = *(const float4*)(wr + kt * 64 + quad * 16 + u4 * 4);
                    m = fmaxf(m, fmaxf(fmaxf(fabsf(v.x), fabsf(v.y)),
                                       fmaxf(fabsf(v.z), fabsf(v.w))));
                }
            m = fmaxf(m, __shfl_xor(m, 16));    // full row spans all 4 quads
            m = fmaxf(m, __shfl_xor(m, 32));
            float inv = m > 1e-30f ? 127.f / m : 0.f;
            float sc  = m * (1.f / 16129.f);
            #pragma unroll
            for (int kt = 0; kt < 4; ++kt) {
                int pk[4];
                #pragma unroll
                for (int u4 = 0; u4 < 4; ++u4) {
                    float4 v = *(const float4*)(wr + kt * 64 + quad * 16 + u4 * 4);
                    int q0 = (int)rintf(fminf(fmaxf(v.x * inv, -127.f), 127.f));
                    int q1 = (int)rintf(fminf(fmaxf(v.y * inv, -127.f), 127.f));
                    int q2 = (int)rintf(fminf(fmaxf(v.z * inv, -127.f), 127.f));
                    int q3 = (int)rintf(fminf(fmaxf(v.w * inv, -127.f), 127.f));
                    pk[u4] = (q0 & 255) | ((q1 & 255) << 8) | ((q2 & 255) << 16) | (q3 << 24);
                }
                i32x4 t = { pk[0], pk[1], pk[2], pk[3] };
                if (g == 0) Br[i][kt] = t; else Bz[i][kt] = t;
            }
            if (i == i16) { if (g == 0) scR = sc; else scZ = sc; }
        }
    }

    float hreg = (t0 == 0) ? 0.f : hstate[b * HH + j];
    if (lane < 32) {
        hBuf[0][j] = f2bf(hreg);
        float hc = fminf(fmaxf(hreg, -1.f), 1.f);
        ((char*)hqBuf[0])[j] = (char)(int)rintf(hc * 127.f);
    }
    const float bhn = b_hh[512 + j];
    const u16* xgb = xg + (size_t)b * Tc * G3;
    float* outb = out + (size_t)b * TT * HH;

    // 2-deep xg prefetch (upper half-wave duplicates lower -> same cachelines)
    float pr0 = bf2f(xgb[j]),      pz0 = bf2f(xgb[256 + j]),      pn0 = bf2f(xgb[512 + j]);
    float pr1 = bf2f(xgb[G3 + j]), pz1 = bf2f(xgb[G3 + 256 + j]), pn1 = bf2f(xgb[G3 + 512 + j]);
    __syncthreads();   // once: weight/h init visible

    for (int tc = 0; tc < Tc; tc += 2) {
        GRU_STEP(tc,     hBuf[0], hBuf[1], hqBuf[0], hqBuf[1], pr0, pz0, pn0);
        GRU_STEP(tc + 1, hBuf[1], hBuf[0], hqBuf[1], hqBuf[0], pr1, pz1, pn1);
    }

    if (t0 + Tc < TT && lane < 32)      // only needed across chunks
        hstate[b * HH + j] = hreg;
}

extern "C" void kernel_launch(void* const* d_in, const int* in_sizes, int n_in,
                              void* d_out, int out_size, void* d_ws, size_t ws_size,
                              hipStream_t stream) {
    const float* x    = (const float*)d_in[0];
    const float* W_ih = (const float*)d_in[1];
    const float* W_hh = (const float*)d_in[2];
    const float* b_ih = (const float*)d_in[3];
    const float* b_hh = (const float*)d_in[4];
    float* out = (float*)d_out;                    // fp32 output [B,T,H]

    float* hstate = (float*)d_ws;                  // 256*256 fp32 = 256 KB
    u16* xg = (u16*)((char*)d_ws + 262144);        // [256*Tc, 768] bf16
    size_t avail = ws_size > 262144 ? ws_size - 262144 : 0;

    int Tc = TT, lt = 9;                           // shrink chunk to fit ws
    while (Tc > 4 && (size_t)256 * Tc * G3 * 2 > avail) { Tc >>= 1; --lt; }

    for (int t0 = 0; t0 < TT; t0 += Tc) {
        // rows = 256*Tc, 1024 rows/block -> grid.x = Tc/4; grid.y = 2 (384 cols each)
        xg_gemm<<<dim3(Tc / 4, 2), 256, 0, stream>>>(
            x, W_ih, b_ih, b_hh, xg, t0, lt);
        gru_seq<<<dim3(256), 512, 0, stream>>>(
            W_hh, b_hh, xg, out, hstate, t0, Tc);
    }
}